// Round 1
// baseline (126.714 us; speedup 1.0000x reference)
//
#include <hip/hip_runtime.h>

// CBOWSubword: out[t,:] = W[seq[t],:] + W[pre[t],:] + W[post[t],:]
// B*S = 131072 tokens, D = 128 fp32 (= 32 float4 per row).
// Mapping: 32 threads per token, one float4 per thread per row.
// Memory-bound: ~64 MiB write + ~51 MiB table fetch (L3-resident).

#define D4 32  // 128 floats / 4 per float4

__global__ __launch_bounds__(256) void cbow_gather3_kernel(
    const int* __restrict__ seq,
    const int* __restrict__ pre,
    const int* __restrict__ post,
    const float4* __restrict__ weight,
    float4* __restrict__ out,
    int n_tokens)
{
    int tid = blockIdx.x * blockDim.x + threadIdx.x;
    int token = tid >> 5;      // 32 threads per token
    int lane  = tid & 31;      // which float4 of the 128-float row
    if (token >= n_tokens) return;

    int s = seq[token];
    int p = pre[token];
    int q = post[token];

    float4 a = weight[(size_t)s * D4 + lane];
    float4 b = weight[(size_t)p * D4 + lane];
    float4 c = weight[(size_t)q * D4 + lane];

    float4 r;
    r.x = a.x + b.x + c.x;
    r.y = a.y + b.y + c.y;
    r.z = a.z + b.z + c.z;
    r.w = a.w + b.w + c.w;

    out[(size_t)token * D4 + lane] = r;
}

extern "C" void kernel_launch(void* const* d_in, const int* in_sizes, int n_in,
                              void* d_out, int out_size, void* d_ws, size_t ws_size,
                              hipStream_t stream)
{
    const int*    seq    = (const int*)d_in[0];
    const int*    pre    = (const int*)d_in[1];
    const int*    post   = (const int*)d_in[2];
    const float4* weight = (const float4*)d_in[3];
    float4*       out    = (float4*)d_out;

    const int n_tokens = in_sizes[0];          // 128*1024 = 131072
    const long total_threads = (long)n_tokens * 32;
    const int block = 256;
    const int grid = (int)((total_threads + block - 1) / block);

    cbow_gather3_kernel<<<grid, block, 0, stream>>>(seq, pre, post, weight, out, n_tokens);
}